// Round 6
// baseline (2807.098 us; speedup 1.0000x reference)
//
#include <hip/hip_runtime.h>
#include <stdint.h>

// StackedRNN depth-3, B=16, T=2048, H=256. Inputs fp32, output fp32.
// Feeder/recurrent split: per stage, 2 feeder WGs precompute
// preact[t] = W_ih @ inp_t + b into a 64-step fp32 ring (d_ws), and one
// recurrent WG runs h_t = tanh(preact[t] + W_hh @ h_{t-1}) with only the
// 128-MFMA W_hh GEMM on the serial chain (~621 cy/step CU matrix-pipe floor
// vs 1242 for the fused form). 9 WGs total, agent-scope flag pipeline.
// ws usage: [0,4096) flags, [8192, 8192+3.15MB) preact rings.

#define TT 2048
#define HH 256
#define RING 64
#define NCH (TT / 8)

typedef _Float16 h16x8 __attribute__((ext_vector_type(8)));
typedef float f32x4 __attribute__((ext_vector_type(4)));

__device__ __forceinline__ unsigned pkrtz(float a, float b) {
  return __builtin_bit_cast(unsigned, __builtin_amdgcn_cvt_pkrtz(a, b));
}

// tanh(x) = 1 - 2e/(1+e), e = exp2(-2*log2e*x). ~1e-6 err; clamp keeps e finite.
__device__ __forceinline__ float tanh_fast(float x) {
  float xm = fmaxf(x, -15.0f);
  float e = __builtin_amdgcn_exp2f(xm * -2.88539008177793f);
  float r = __builtin_amdgcn_rcpf(1.0f + e);
  return __builtin_fmaf(-2.0f * e, r, 1.0f);
}

__device__ __forceinline__ void spin_ge(int* p, int need) {
  while (__hip_atomic_load(p, __ATOMIC_ACQUIRE, __HIP_MEMORY_SCOPE_AGENT) < need)
    __builtin_amdgcn_s_sleep(2);
}

// LDS B layout (fp16, K=256): granule (16B) for (k,n): u=(k>>5)*4+((k>>3)&3),
// j=k&7; half-index = (u*16 + (n ^ (u&7)))*8 + j. XOR swizzle: writes spread,
// fragment reads (fixed u) conflict-free. HW-validated in R5.
__global__ __launch_bounds__(512, 2)
void stacked_rnn(const float* __restrict__ x,
                 const int* __restrict__ seq_lens,
                 const float* __restrict__ Wih,
                 const float* __restrict__ Whh,
                 const float* __restrict__ bias,
                 float* __restrict__ out,
                 int* __restrict__ flags,
                 float* __restrict__ ring) {
  const int bid = blockIdx.x;
  const int tid = (int)threadIdx.x;
  const int w = tid >> 6;              // wave 0..7 -> rows [32w, 32w+32)
  const int lane = tid & 63;
  const int q = lane >> 4;
  const int n = lane & 15;             // batch column

  const bool is_rec = (bid < 3);
  const int ks = is_rec ? bid : ((bid - 3) >> 1);

  __shared__ unsigned short Bsm[2][4096];   // 2 x 8KB ping-pong

  // ---- persistent weight A-fragments (fp16): W_hh for rec, W_ih for feeder
  const float* Wsel = (is_rec ? Whh : Wih) + ks * HH * HH;
  h16x8 wf[2][8];
#pragma unroll
  for (int mti = 0; mti < 2; ++mti) {
    const int fA = w * 32 + mti * 16 + n;      // A row = lane&15
#pragma unroll
    for (int kt = 0; kt < 8; ++kt) {
      const float* src = Wsel + fA * HH + kt * 32 + q * 8;  // A k = quad*8+j
      float4 a0 = ((const float4*)src)[0];
      float4 a1 = ((const float4*)src)[1];
      h16x8 f;
      f[0] = (_Float16)a0.x; f[1] = (_Float16)a0.y;
      f[2] = (_Float16)a0.z; f[3] = (_Float16)a0.w;
      f[4] = (_Float16)a1.x; f[5] = (_Float16)a1.y;
      f[6] = (_Float16)a1.z; f[7] = (_Float16)a1.w;
      wf[mti][kt] = f;
    }
  }

  // ---- fragment read offsets (halves): frag kt at rd{E,O} + kt*512
  const int rdE = (q * 16 + (n ^ q)) * 8;
  const int rdO = (q * 16 + (n ^ q ^ 4)) * 8;

  float* ringk = ring + ks * (RING * 4096);
  const int prow = n * 256 + w * 32 + q * 4;   // preact[slot][n][row]

  int* rec_flag_me = flags + ks * 16;
  int* feed_base = flags + 64 + ks * NCH;

  if (is_rec) {
    // ================= recurrent workgroup =================
    const int sl = seq_lens[n];
    int hofs[2];
#pragma unroll
    for (int mti = 0; mti < 2; ++mti) {
      const int u = w * 4 + mti * 2 + (q >> 1);
      hofs[mti] = (u * 16 + (n ^ (u & 7))) * 8 + (q & 1) * 4;
    }
    for (int i = tid; i < 4096; i += 512) Bsm[0][i] = 0;   // h_{-1}=0

    if (tid == 0) { spin_ge(feed_base + 0, 1); spin_ge(feed_base + 1, 2); }
    __syncthreads();

    f32x4 pf0 = *(const f32x4*)(ringk + prow);
    f32x4 pf1 = *(const f32x4*)(ringk + prow + 16);

    float* outp = out + ((n * TT) * 3 + ks) * HH + w * 32 + q * 4;

    for (int t = 0; t < TT; ++t) {
      if ((t & 7) == 0 && t > 0) {
        if (tid == 0) {
          __hip_atomic_store(rec_flag_me, t, __ATOMIC_RELEASE,
                             __HIP_MEMORY_SCOPE_AGENT);
          const int c = t >> 3;
          spin_ge(feed_base + c, c + 1);            // chunk c ready
          if (c + 1 < NCH) spin_ge(feed_base + c + 1, c + 2);  // + prefetch cover
        }
        __syncthreads();
      }

      // prefetch preact for t+1 (covered by chunk gate)
      f32x4 pA0, pA1;
      if (t + 1 < TT) {
        const float* pb = ringk + ((t + 1) & (RING - 1)) * 4096 + prow;
        pA0 = *(const f32x4*)pb;
        pA1 = *(const f32x4*)(pb + 16);
      }

      // GEMM: acc = preact_t + W_hh @ h_{t-1}
      const unsigned short* Bp = Bsm[t & 1];
      f32x4 acc0 = pf0, acc1 = pf1;
#pragma unroll
      for (int kt = 0; kt < 8; ++kt) {
        h16x8 bf = *(const h16x8*)&Bp[((kt & 1) ? rdO : rdE) + kt * 512];
        acc0 = __builtin_amdgcn_mfma_f32_16x16x32_f16(wf[0][kt], bf, acc0, 0, 0, 0);
        acc1 = __builtin_amdgcn_mfma_f32_16x16x32_f16(wf[1][kt], bf, acc1, 0, 0, 0);
      }

      // tanh + masked fp32 store (h kept unmasked for recurrence)
      const bool live = (t < sl);
      uint2 hpk[2];
      f32x4 accs[2] = {acc0, acc1};
#pragma unroll
      for (int mti = 0; mti < 2; ++mti) {
        float h0 = tanh_fast(accs[mti][0]);
        float h1 = tanh_fast(accs[mti][1]);
        float h2 = tanh_fast(accs[mti][2]);
        float h3 = tanh_fast(accs[mti][3]);
        hpk[mti].x = pkrtz(h0, h1);
        hpk[mti].y = pkrtz(h2, h3);
        float4 od;
        od.x = live ? h0 : 0.0f;
        od.y = live ? h1 : 0.0f;
        od.z = live ? h2 : 0.0f;
        od.w = live ? h3 : 0.0f;
        *(float4*)(outp + mti * 16) = od;
      }
      outp += 3 * HH;

      if (t + 1 < TT) {
        unsigned short* Bq = Bsm[(t & 1) ^ 1];
        *(uint2*)&Bq[hofs[0]] = hpk[0];
        *(uint2*)&Bq[hofs[1]] = hpk[1];
        pf0 = pA0; pf1 = pA1;
      }
      __syncthreads();
    }
    if (tid == 0)
      __hip_atomic_store(rec_flag_me, TT, __ATOMIC_RELEASE,
                         __HIP_MEMORY_SCOPE_AGENT);
  } else {
    // ================= feeder workgroup =================
    const int fid = (bid - 3) & 1;   // handles chunks c ≡ fid (mod 2)

    f32x4 biasv[2];
#pragma unroll
    for (int mti = 0; mti < 2; ++mti)
#pragma unroll
      for (int r = 0; r < 4; ++r)
        biasv[mti][r] = bias[ks * HH + w * 32 + mti * 16 + q * 4 + r];

    // loader: thread (n_l, k8) handles col n_l, k in [k8*8, k8*8+8)
    const int n_l = tid >> 5, k8 = tid & 31;
    const int u_l = (k8 >> 2) * 4 + (k8 & 3);
    const int ldst = (u_l * 16 + (n_l ^ (u_l & 7))) * 8;
    const float* src_base;
    int sstr;
    if (ks == 0) { src_base = x + ((n_l * TT) << 8) + (k8 << 3); sstr = HH; }
    else { src_base = out + (((n_l * TT) * 3 + (ks - 1)) << 8) + (k8 << 3); sstr = 3 * HH; }

    int* rec_flag_up = flags + (ks - 1) * 16;

    for (int c = fid; c < NCH; c += 2) {
      const int t0 = c * 8;
      if (tid == 0) {
        if (ks > 0) spin_ge(rec_flag_up, t0 + 8);           // input h ready
        if (t0 >= RING) spin_ge(rec_flag_me, t0 - (RING - 8));  // ring guard
      }
      __syncthreads();

      // stage inp_{t0} -> buf0
      {
        const float* s = src_base + t0 * sstr;
        float4 c0 = ((const float4*)s)[0], c1 = ((const float4*)s)[1];
        *(uint4*)&Bsm[0][ldst] = make_uint4(pkrtz(c0.x, c0.y), pkrtz(c0.z, c0.w),
                                            pkrtz(c1.x, c1.y), pkrtz(c1.z, c1.w));
      }
      __syncthreads();

      for (int s = 0; s < 8; ++s) {
        const int t = t0 + s;
        float4 i0, i1;
        if (s < 7) {
          const float* sp = src_base + (t + 1) * sstr;
          i0 = ((const float4*)sp)[0];
          i1 = ((const float4*)sp)[1];
        }
        const unsigned short* Bp = Bsm[s & 1];
        f32x4 acc0 = biasv[0], acc1 = biasv[1];
#pragma unroll
        for (int kt = 0; kt < 8; ++kt) {
          h16x8 bf = *(const h16x8*)&Bp[((kt & 1) ? rdO : rdE) + kt * 512];
          acc0 = __builtin_amdgcn_mfma_f32_16x16x32_f16(wf[0][kt], bf, acc0, 0, 0, 0);
          acc1 = __builtin_amdgcn_mfma_f32_16x16x32_f16(wf[1][kt], bf, acc1, 0, 0, 0);
        }
        float* pd = ringk + (t & (RING - 1)) * 4096 + prow;
        *(f32x4*)pd = acc0;
        *(f32x4*)(pd + 16) = acc1;
        if (s < 7) {
          unsigned short* Bq = Bsm[(s & 1) ^ 1];
          *(uint4*)&Bq[ldst] = make_uint4(pkrtz(i0.x, i0.y), pkrtz(i0.z, i0.w),
                                          pkrtz(i1.x, i1.y), pkrtz(i1.z, i1.w));
        }
        __syncthreads();   // drains preact stores (vmcnt) + LDS reuse
      }
      if (tid == 0)
        __hip_atomic_store(feed_base + c, c + 1, __ATOMIC_RELEASE,
                           __HIP_MEMORY_SCOPE_AGENT);
    }
  }
}

extern "C" void kernel_launch(void* const* d_in, const int* in_sizes, int n_in,
                              void* d_out, int out_size, void* d_ws, size_t ws_size,
                              hipStream_t stream) {
  (void)in_sizes; (void)n_in; (void)out_size; (void)ws_size;
  const float* x   = (const float*)d_in[0];
  const int*   sl  = (const int*)d_in[1];
  const float* wih = (const float*)d_in[2];
  const float* whh = (const float*)d_in[3];
  const float* b   = (const float*)d_in[4];

  // flags in [0,4096); preact rings at +8192 (3 stages x 64 x 4096 fp32 ~ 3.1MB)
  (void)hipMemsetAsync(d_ws, 0, 4096, stream);
  float* ring = (float*)((char*)d_ws + 8192);
  hipLaunchKernelGGL(stacked_rnn, dim3(9), dim3(512), 0, stream,
                     x, sl, wih, whh, b, (float*)d_out, (int*)d_ws, ring);
}